// Round 9
// baseline (152.613 us; speedup 1.0000x reference)
//
#include <hip/hip_runtime.h>

// Transformer block on MI355X. fp32 in/out; fp8-e4m3 flash-attn core.
// B=4 N=2048 C=64 H=8 D=64 HS=512.
// ws (bytes): Qfp8[4M] Kfp8[4M] VTfp8[4M] part_bf16[16M] lsum_f32[1M].
// Q,K PRE-SCALED by sqrt(1/(8*ln2)): P = exp2(S_mfma) = exp(S_raw/8).
// V stored transposed (b,h,d,n). Attention t-range split in 2 chunks/block;
// blocks emit UNNORMALIZED per-head out-proj partials + row-sums l.

#define NN 2048
#define CC 64
#define HH 8
#define HSZ 512
#define QKSCALE 0.42466092f

typedef __bf16 bf16x8 __attribute__((ext_vector_type(8)));
typedef float f32x4 __attribute__((ext_vector_type(4)));

__device__ __forceinline__ float b2f(unsigned short u) {
  union { unsigned int i; float f; } v; v.i = ((unsigned int)u) << 16; return v.f;
}
__device__ __forceinline__ unsigned short f2b(float f) {
  union { float f; unsigned int i; } v; v.f = f;
  unsigned int r = v.i + 0x7FFFu + ((v.i >> 16) & 1u);
  return (unsigned short)(r >> 16);
}
__device__ __forceinline__ unsigned int pk2(float a, float b) {
  return (unsigned int)f2b(a) | ((unsigned int)f2b(b) << 16);
}
__device__ __forceinline__ unsigned char f2fp8(float f) {
  int p = __builtin_amdgcn_cvt_pk_fp8_f32(f, f, 0, false);
  return (unsigned char)(p & 0xFF);
}
__device__ __forceinline__ float gelu_f(float x) {
  return 0.5f * x * (1.0f + erff(x * 0.7071067811865475f));
}

// ---------------- Kernel 1: LN1 + fused QKV (MFMA GEMM, fp8 out) ----------------
// grid = 12 n-windows(128) x 128 m-blocks(64). block 256 = 4 waves x 16 rows.
// fp8 staging buffer aliased onto As -> LDS 27.6KB, 5 blocks/CU.
__global__ __launch_bounds__(256) void k_ln_qkv(
    const float* __restrict__ x,
    const float* __restrict__ g1,
    const float* __restrict__ be1,
    const float* __restrict__ W,
    const float* __restrict__ bqkv,
    unsigned char* __restrict__ Qb,
    unsigned char* __restrict__ Kb,
    unsigned char* __restrict__ VbT)
{
  __shared__ __align__(16) unsigned short As[64 * 72];   // y bf16 [row][k]; aliased by Es
  __shared__ __align__(16) unsigned short Ws[128 * 72];  // W^T bf16 [n][k]
  unsigned char* Es = (unsigned char*)As;                // 8192B fp8 out staging
  const int tid = threadIdx.x, wv = tid >> 6, lane = tid & 63;
  const int col = lane & 15, quad = lane >> 4;
  const int bm = blockIdx.x & 127, bn = blockIdx.x >> 7;
  const int m0 = bm * 64, nw = bn * 128;

  // ---- A staging + LN ----
  const int c4 = tid & 15;
  float4 gv = *(const float4*)(g1 + c4 * 4);
  float4 bv = *(const float4*)(be1 + c4 * 4);
  #pragma unroll
  for (int s = 0; s < 4; ++s) {
    int idx = s * 256 + tid;
    int row = idx >> 4;
    float4 xv = *(const float4*)(x + (size_t)(m0 + row) * CC + c4 * 4);
    float ps = xv.x + xv.y + xv.z + xv.w;
    float ps2 = xv.x * xv.x + xv.y * xv.y + xv.z * xv.z + xv.w * xv.w;
    #pragma unroll
    for (int off = 8; off; off >>= 1) {
      ps += __shfl_xor(ps, off, 16);
      ps2 += __shfl_xor(ps2, off, 16);
    }
    float mean = ps * (1.0f / 64.0f);
    float var = ps2 * (1.0f / 64.0f) - mean * mean;
    float rs = rsqrtf(var + 1e-6f);
    uint2 packed;
    packed.x = pk2((xv.x - mean) * rs * gv.x + bv.x, (xv.y - mean) * rs * gv.y + bv.y);
    packed.y = pk2((xv.z - mean) * rs * gv.z + bv.z, (xv.w - mean) * rs * gv.w + bv.w);
    *(uint2*)&As[row * 72 + c4 * 4] = packed;
  }

  // ---- W staging ----
  {
    const int c_loc = tid & 127;
    const int kg = tid >> 7;
    const int ng = nw + c_loc;
    #pragma unroll
    for (int g = 0; g < 4; ++g) {
      float wv8[8];
      #pragma unroll
      for (int j = 0; j < 8; ++j) wv8[j] = W[(size_t)(kg * 32 + g * 8 + j) * 1536 + ng];
      uint4 u;
      u.x = pk2(wv8[0], wv8[1]); u.y = pk2(wv8[2], wv8[3]);
      u.z = pk2(wv8[4], wv8[5]); u.w = pk2(wv8[6], wv8[7]);
      *(uint4*)&Ws[c_loc * 72 + kg * 32 + g * 8] = u;
    }
  }
  __syncthreads();

  // ---- MFMA: 1 m-tile x 8 n-tiles, K=64 ----
  bf16x8 af0 = *(const bf16x8*)&As[(wv * 16 + col) * 72 + quad * 8];
  bf16x8 af1 = *(const bf16x8*)&As[(wv * 16 + col) * 72 + 32 + quad * 8];

  f32x4 acc[8];
  #pragma unroll
  for (int nt = 0; nt < 8; ++nt) acc[nt] = (f32x4){0.f, 0.f, 0.f, 0.f};
  #pragma unroll
  for (int nt = 0; nt < 8; ++nt) {
    bf16x8 b0 = *(const bf16x8*)&Ws[(nt * 16 + col) * 72 + quad * 8];
    bf16x8 b1 = *(const bf16x8*)&Ws[(nt * 16 + col) * 72 + 32 + quad * 8];
    acc[nt] = __builtin_amdgcn_mfma_f32_16x16x32_bf16(af0, b0, acc[nt], 0, 0, 0);
    acc[nt] = __builtin_amdgcn_mfma_f32_16x16x32_bf16(af1, b1, acc[nt], 0, 0, 0);
  }
  __syncthreads();  // all As reads done before Es (alias) is written

  // ---- epilogue: bias -> fp8 -> LDS staging -> coalesced flush ----
  const int bb = m0 >> 11;
  const int nloc = m0 & 2047;
  const int which = nw >> 9;            // block-uniform: 0=Q 1=K 2=V
  const int hbase = (nw >> 6) & 7;
  const int tloc = wv * 16 + quad * 4;  // local token of r=0

  if (which == 2) {
    // V: pack 4 tokens/dword into Es[hb][d][n-chunk], flush as 64B segments
    #pragma unroll
    for (int nt = 0; nt < 8; ++nt) {
      const int hb = nt >> 2, d0 = (nt & 3) * 16;
      const float bias = bqkv[nw + nt * 16 + col];
      int lo = __builtin_amdgcn_cvt_pk_fp8_f32(acc[nt][0] + bias, acc[nt][1] + bias, 0, false);
      int full = __builtin_amdgcn_cvt_pk_fp8_f32(acc[nt][2] + bias, acc[nt][3] + bias, lo, true);
      *(unsigned int*)&Es[hb * 4096 + (d0 + col) * 64 + tloc] = (unsigned int)full;
    }
    __syncthreads();
    const int d = tid >> 2, nseg = (tid & 3) * 16;
    #pragma unroll
    for (int hb = 0; hb < 2; ++hb) {
      size_t off = ((size_t)(bb * HH + hbase + hb) * CC + d) * NN + nloc + nseg;
      *(uint4*)(VbT + off) = *(const uint4*)&Es[hb * 4096 + tid * 16];
    }
  } else {
    // Q/K: fp8 bytes into Es[hb][token][d], flush 4KB contiguous per hb
    const float scale = (which == 0) ? QKSCALE : 1.0f;
    #pragma unroll
    for (int nt = 0; nt < 8; ++nt) {
      const int hb = nt >> 2, d0 = (nt & 3) * 16;
      const float bias = bqkv[nw + nt * 16 + col];
      #pragma unroll
      for (int r = 0; r < 4; ++r)
        Es[hb * 4096 + (tloc + r) * 64 + d0 + col] = f2fp8((acc[nt][r] + bias) * scale);
    }
    __syncthreads();
    unsigned char* dst = (which == 0) ? Qb : Kb;
    #pragma unroll
    for (int hb = 0; hb < 2; ++hb) {
      size_t off = ((size_t)(bb * HH + hbase + hb) * NN + nloc) * CC + tid * 16;
      *(uint4*)(dst + off) = *(const uint4*)&Es[hb * 4096 + tid * 16];
    }
  }
}

// ---------------- Kernel 2: fp8 flash attention, dbuf single-barrier ----------------
// grid = 1024: bh(32) x qc(16, 128 q) x tc(2, 1024 t). block 256 = 4 waves x 32 q.
// S^T = K.Q^T; P^T B-frags via shfl (no LDS). O^T = V^T.P^T. lsum via ones-row MFMA.
// K/V staging double-buffered: prefetch regs at iter top, one barrier per iter.
__global__ __launch_bounds__(256) void k_attn(
    const unsigned char* __restrict__ Q,
    const unsigned char* __restrict__ K,
    const unsigned char* __restrict__ VT,
    const float* __restrict__ Wout,
    unsigned short* __restrict__ part,
    float* __restrict__ lsums)
{
  __shared__ __align__(16) unsigned char smem[27648];
  // dbuf layout: buf b at smem + b*11520: Ks[64*80], Vt[80*80] ([d][t], +ones rows)
  unsigned short* Wb = (unsigned short*)smem;           // epi: 64*72*2 = 9216
  unsigned short* Ob = (unsigned short*)(smem + 9216);  // epi: 4*32*72*2 = 18432
  const int tid = threadIdx.x, wv = tid >> 6, lane = tid & 63;
  const int col = lane & 15, quad = lane >> 4;
  const int bid = blockIdx.x;
  const int tc = bid & 1, qc = (bid >> 1) & 15, bh = bid >> 5;
  const size_t base = (size_t)bh * NN * CC;
  const int q0 = qc * 128 + wv * 32;
  const int t0 = tc * 1024;
  const int srow = tid >> 2, sc16 = (tid & 3) << 4;

  // ones row (d=64) + zero rows (65..79) in BOTH Vt buffers
  if (tid < 160) {
    int bsel = tid >= 80, t2 = tid - bsel * 80;
    unsigned int fill = (t2 < 5) ? 0x38383838u : 0u;  // fp8 e4m3 1.0 = 0x38
    uint4 u; u.x = fill; u.y = fill; u.z = fill; u.w = fill;
    *(uint4*)&smem[bsel * 11520 + 5120 + 64 * 80 + t2 * 16] = u;
  }

  // Q B-frags (n = q-row = col, k = d = quad*8+j + 32*kh)
  long qf[2][2];
  #pragma unroll
  for (int mt = 0; mt < 2; ++mt)
    #pragma unroll
    for (int kh = 0; kh < 2; ++kh)
      qf[mt][kh] = *(const long*)(Q + base + (size_t)(q0 + mt * 16 + col) * CC + kh * 32 + quad * 8);

  f32x4 o[2][4];
  f32x4 ol[2];
  #pragma unroll
  for (int mt = 0; mt < 2; ++mt) {
    #pragma unroll
    for (int dt = 0; dt < 4; ++dt) o[mt][dt] = (f32x4){0.f, 0.f, 0.f, 0.f};
    ol[mt] = (f32x4){0.f, 0.f, 0.f, 0.f};
  }
  const int sl0 = ((quad & 1) << 5) + col;  // src lane quad'=2*(quad&1)
  const int sl1 = sl0 + 16;                 // quad'+1
  const bool hiq = (quad >= 2);

  // prologue: stage tile 0
  {
    *(uint4*)&smem[srow * 80 + sc16] =
        *(const uint4*)(K + base + (size_t)(t0 + srow) * CC + sc16);
    *(uint4*)&smem[5120 + srow * 80 + sc16] =
        *(const uint4*)(VT + base + (size_t)srow * NN + t0 + sc16);
  }
  __syncthreads();

  for (int kt = 0; kt < 16; ++kt) {
    unsigned char* Ks = smem + (kt & 1) * 11520;
    unsigned char* Vt = Ks + 5120;
    // prefetch next tile into registers (VMEM overlaps compute)
    uint4 kreg, vreg;
    const bool more = (kt + 1) < 16;
    if (more) {
      const int tb2 = t0 + (kt + 1) * 64;
      kreg = *(const uint4*)(K + base + (size_t)(tb2 + srow) * CC + sc16);
      vreg = *(const uint4*)(VT + base + (size_t)srow * NN + tb2 + sc16);
    }

    // S^T tiles -> P fp8, packed per-lane
    unsigned int Dw[2][4];
    #pragma unroll
    for (int ct = 0; ct < 4; ++ct) {
      long k0 = *(const long*)&Ks[(ct * 16 + col) * 80 + quad * 8];
      long k1 = *(const long*)&Ks[(ct * 16 + col) * 80 + 32 + quad * 8];
      #pragma unroll
      for (int mt = 0; mt < 2; ++mt) {
        f32x4 a = (f32x4){0.f, 0.f, 0.f, 0.f};
        a = __builtin_amdgcn_mfma_f32_16x16x32_fp8_fp8(k0, qf[mt][0], a, 0, 0, 0);
        a = __builtin_amdgcn_mfma_f32_16x16x32_fp8_fp8(k1, qf[mt][1], a, 0, 0, 0);
        float p0 = __builtin_amdgcn_exp2f(a[0]);
        float p1 = __builtin_amdgcn_exp2f(a[1]);
        float p2 = __builtin_amdgcn_exp2f(a[2]);
        float p3 = __builtin_amdgcn_exp2f(a[3]);
        int lo = __builtin_amdgcn_cvt_pk_fp8_f32(p0, p1, 0, false);
        Dw[mt][ct] = (unsigned int)__builtin_amdgcn_cvt_pk_fp8_f32(p2, p3, lo, true);
      }
    }

    // O^T += V^T . P^T ; lsum row via ones-row MFMA
    #pragma unroll
    for (int kh = 0; kh < 2; ++kh) {
      long pb[2];
      #pragma unroll
      for (int mt = 0; mt < 2; ++mt) {
        unsigned int a0 = (unsigned int)__shfl((int)Dw[mt][2 * kh], sl0, 64);
        unsigned int b0 = (unsigned int)__shfl((int)Dw[mt][2 * kh + 1], sl0, 64);
        unsigned int a1 = (unsigned int)__shfl((int)Dw[mt][2 * kh], sl1, 64);
        unsigned int b1 = (unsigned int)__shfl((int)Dw[mt][2 * kh + 1], sl1, 64);
        unsigned long lo = hiq ? b0 : a0;
        unsigned long hi = hiq ? b1 : a1;
        pb[mt] = (long)(lo | (hi << 32));
      }
      #pragma unroll
      for (int dt = 0; dt < 4; ++dt) {
        long vf = *(const long*)&Vt[(dt * 16 + col) * 80 + kh * 32 + quad * 8];
        o[0][dt] = __builtin_amdgcn_mfma_f32_16x16x32_fp8_fp8(vf, pb[0], o[0][dt], 0, 0, 0);
        o[1][dt] = __builtin_amdgcn_mfma_f32_16x16x32_fp8_fp8(vf, pb[1], o[1][dt], 0, 0, 0);
      }
      long vl = *(const long*)&Vt[(64 + col) * 80 + kh * 32 + quad * 8];
      ol[0] = __builtin_amdgcn_mfma_f32_16x16x32_fp8_fp8(vl, pb[0], ol[0], 0, 0, 0);
      ol[1] = __builtin_amdgcn_mfma_f32_16x16x32_fp8_fp8(vl, pb[1], ol[1], 0, 0, 0);
    }

    // write prefetched tile to the other buffer, one barrier per iter
    if (more) {
      unsigned char* Kn = smem + ((kt + 1) & 1) * 11520;
      *(uint4*)&Kn[srow * 80 + sc16] = kreg;
      *(uint4*)&Kn[5120 + srow * 80 + sc16] = vreg;
    }
    __syncthreads();
  }

  // l[q] from ones-row tile (quad 0, reg 0)
  const int h = bh & 7, b = bh >> 3;
  #pragma unroll
  for (int mt = 0; mt < 2; ++mt) {
    if (quad == 0)
      lsums[(size_t)(tc * 32 + bh) * NN + q0 + mt * 16 + col] = ol[mt][0];
  }

  // ---- fused per-head out-proj on UNNORMALIZED O ----
  {
    const int c = tid & 63, kg = tid >> 6;
    #pragma unroll
    for (int j = 0; j < 16; ++j)
      Wb[c * 72 + kg * 16 + j] = f2b(Wout[(size_t)(h * 64 + kg * 16 + j) * 64 + c]);
  }
  unsigned short* Obw = Ob + wv * (32 * 72);
  #pragma unroll
  for (int mt = 0; mt < 2; ++mt)
    #pragma unroll
    for (int dt = 0; dt < 4; ++dt) {
      uint2 u;
      u.x = pk2(o[mt][dt][0], o[mt][dt][1]);
      u.y = pk2(o[mt][dt][2], o[mt][dt][3]);
      *(uint2*)&Obw[(mt * 16 + col) * 72 + dt * 16 + quad * 4] = u;
    }
  __syncthreads();

  #pragma unroll
  for (int mt = 0; mt < 2; ++mt) {
    bf16x8 oa0 = *(const bf16x8*)&Obw[(mt * 16 + col) * 72 + quad * 8];
    bf16x8 oa1 = *(const bf16x8*)&Obw[(mt * 16 + col) * 72 + 32 + quad * 8];
    #pragma unroll
    for (int nt = 0; nt < 4; ++nt) {
      bf16x8 bw0 = *(const bf16x8*)&Wb[(nt * 16 + col) * 72 + quad * 8];
      bf16x8 bw1 = *(const bf16x8*)&Wb[(nt * 16 + col) * 72 + 32 + quad * 8];
      f32x4 ac = (f32x4){0.f, 0.f, 0.f, 0.f};
      ac = __builtin_amdgcn_mfma_f32_16x16x32_bf16(oa0, bw0, ac, 0, 0, 0);
      ac = __builtin_amdgcn_mfma_f32_16x16x32_bf16(oa1, bw1, ac, 0, 0, 0);
      #pragma unroll
      for (int r = 0; r < 4; ++r) {
        int n = q0 + mt * 16 + quad * 4 + r;
        part[((size_t)(tc * 32 + bh) * NN + n) * CC + nt * 16 + col] = f2b(ac[r]);
      }
    }
  }
}

// ---------------- Kernel 3: sum partials/l + GELU + res + LN2 + MLP + res ----------------
// grid 1024, block 256 = 4 waves, 2 tokens/wave. W1/W2 staged bf16 (20KB LDS, 8 blk/CU).
__global__ __launch_bounds__(256) void k_post(
    const unsigned short* __restrict__ part,
    const float* __restrict__ lsums,
    const float* __restrict__ x,
    const float* __restrict__ bout,
    const float* __restrict__ g2,
    const float* __restrict__ be2,
    const float* __restrict__ W1,
    const float* __restrict__ b1,
    const float* __restrict__ W2,
    const float* __restrict__ b2v,
    float* __restrict__ out)
{
  __shared__ __align__(16) unsigned short Ws1[64 * 64];
  __shared__ __align__(16) unsigned short Ws2[64 * 64];
  __shared__ float ys[8][64], hs[8][64];
  const int tid = threadIdx.x, wid = tid >> 6, lane = tid & 63;
  const int w2 = wid * 2;
  const int tk0 = blockIdx.x * 8 + w2;

  #pragma unroll
  for (int p = 0; p < 4; ++p) {
    int idx = p * 256 + tid;
    float4 a1 = *(const float4*)(W1 + idx * 4);
    float4 a2 = *(const float4*)(W2 + idx * 4);
    uint2 u1; u1.x = pk2(a1.x, a1.y); u1.y = pk2(a1.z, a1.w);
    uint2 u2; u2.x = pk2(a2.x, a2.y); u2.y = pk2(a2.z, a2.w);
    *(uint2*)&Ws1[idx * 4] = u1;
    *(uint2*)&Ws2[idx * 4] = u2;
  }

  const float boutl = bout[lane];
  const float g2l = g2[lane], be2l = be2[lane];
  float x2v[2];
  #pragma unroll
  for (int t = 0; t < 2; ++t) {
    const int tk = tk0 + t;
    const int b = tk >> 11, n = tk & 2047;
    float proj = 0.f;
    #pragma unroll
    for (int h = 0; h < 8; ++h) {
      size_t i0 = (size_t)(b * HH + h) * NN + n;
      size_t i1 = i0 + (size_t)32 * NN;
      float p = b2f(part[i0 * CC + lane]) + b2f(part[i1 * CC + lane]);
      float l = lsums[i0] + lsums[i1];
      proj += p * __builtin_amdgcn_rcpf(l);
    }
    float a = gelu_f(proj + boutl);
    float x2 = a + x[(size_t)tk * CC + lane];
    x2v[t] = x2;
    float s = x2;
    #pragma unroll
    for (int off = 32; off; off >>= 1) s += __shfl_xor(s, off, 64);
    float mean = s * (1.0f / 64.0f);
    float d = x2 - mean;
    float vs = d * d;
    #pragma unroll
    for (int off = 32; off; off >>= 1) vs += __shfl_xor(vs, off, 64);
    float var = vs * (1.0f / 64.0f);
    ys[w2 + t][lane] = d * rsqrtf(var + 1e-6f) * g2l + be2l;
  }
  __syncthreads();  // covers W staging + ys

  float acc2[2] = {0.f, 0.f};
  #pragma unroll 8
  for (int c = 0; c < 64; ++c) {
    float w = b2f(Ws1[c * 64 + lane]);
    acc2[0] += ys[w2][c] * w;
    acc2[1] += ys[w2 + 1][c] * w;
  }
  const float b1l = b1[lane];
  hs[w2][lane] = gelu_f(acc2[0] + b1l);      // same-wave LDS rows: no barrier
  hs[w2 + 1][lane] = gelu_f(acc2[1] + b1l);

  float acc3[2] = {0.f, 0.f};
  #pragma unroll 8
  for (int c = 0; c < 64; ++c) {
    float w = b2f(Ws2[c * 64 + lane]);
    acc3[0] += hs[w2][c] * w;
    acc3[1] += hs[w2 + 1][c] * w;
  }
  const float b2l = b2v[lane];
  #pragma unroll
  for (int t = 0; t < 2; ++t)
    out[(size_t)(tk0 + t) * CC + lane] = acc3[t] + b2l + x2v[t];
}

extern "C" void kernel_launch(void* const* d_in, const int* in_sizes, int n_in,
                              void* d_out, int out_size, void* d_ws, size_t ws_size,
                              hipStream_t stream) {
  const float* x    = (const float*)d_in[0];
  const float* g1   = (const float*)d_in[1];
  const float* be1  = (const float*)d_in[2];
  const float* Wqkv = (const float*)d_in[3];
  const float* bqkv = (const float*)d_in[4];
  const float* Wout = (const float*)d_in[5];
  const float* bout = (const float*)d_in[6];
  const float* g2   = (const float*)d_in[7];
  const float* be2  = (const float*)d_in[8];
  const float* W1   = (const float*)d_in[9];
  const float* b1   = (const float*)d_in[10];
  const float* W2   = (const float*)d_in[11];
  const float* b2   = (const float*)d_in[12];
  float* out = (float*)d_out;

  unsigned char* wsb = (unsigned char*)d_ws;
  const size_t SZ = (size_t)4 * HH * NN * CC;  // 4 MiB
  unsigned char* Qb   = wsb;
  unsigned char* Kb   = wsb + SZ;
  unsigned char* VbT  = wsb + 2 * SZ;
  unsigned short* part = (unsigned short*)(wsb + 3 * SZ);      // 16 MiB bf16
  float* lsums         = (float*)(wsb + 3 * SZ + 4 * SZ);      // 1 MiB f32

  k_ln_qkv<<<1536, 256, 0, stream>>>(x, g1, be1, Wqkv, bqkv, Qb, Kb, VbT);
  k_attn<<<1024, 256, 0, stream>>>(Qb, Kb, VbT, Wout, part, lsums);
  k_post<<<1024, 256, 0, stream>>>(part, lsums, x, bout, g2, be2, W1, b1, W2, b2, out);
}

// Round 10
// 147.254 us; speedup vs baseline: 1.0364x; 1.0364x over previous
//
#include <hip/hip_runtime.h>

// Transformer block on MI355X. fp32 in/out; fp8-e4m3 flash-attn core.
// B=4 N=2048 C=64 H=8 D=64 HS=512.
// ws (bytes): Qfp8[4M] Kfp8[4M] VTfp8[4M] part_bf16[16M] lsum_f32[1M].
// Q,K PRE-SCALED by sqrt(1/(8*ln2)): P = exp2(S_mfma) = exp(S_raw/8).
// V stored transposed (b,h,d,n). Attention t-range split in 2 chunks/block;
// blocks emit UNNORMALIZED per-head out-proj partials + row-sums l.
// LDS row stride 88B (22 dwords): bank-pair = (11*col+quad) mod 16, gcd(11,16)=1
// -> conflict-free b64 fragment reads (stride 80 had inherent 2-way).

#define NN 2048
#define CC 64
#define HH 8
#define HSZ 512
#define QKSCALE 0.42466092f
#define LSTR 88

typedef __bf16 bf16x8 __attribute__((ext_vector_type(8)));
typedef float f32x4 __attribute__((ext_vector_type(4)));

__device__ __forceinline__ float b2f(unsigned short u) {
  union { unsigned int i; float f; } v; v.i = ((unsigned int)u) << 16; return v.f;
}
__device__ __forceinline__ unsigned short f2b(float f) {
  union { float f; unsigned int i; } v; v.f = f;
  unsigned int r = v.i + 0x7FFFu + ((v.i >> 16) & 1u);
  return (unsigned short)(r >> 16);
}
__device__ __forceinline__ unsigned int pk2(float a, float b) {
  return (unsigned int)f2b(a) | ((unsigned int)f2b(b) << 16);
}
__device__ __forceinline__ unsigned char f2fp8(float f) {
  int p = __builtin_amdgcn_cvt_pk_fp8_f32(f, f, 0, false);
  return (unsigned char)(p & 0xFF);
}
__device__ __forceinline__ float gelu_f(float x) {
  return 0.5f * x * (1.0f + erff(x * 0.7071067811865475f));
}

// ---------------- Kernel 1: LN1 + fused QKV (MFMA GEMM, fp8 out) ----------------
// grid = 12 n-windows(128) x 128 m-blocks(64). block 256 = 4 waves x 16 rows.
__global__ __launch_bounds__(256) void k_ln_qkv(
    const float* __restrict__ x,
    const float* __restrict__ g1,
    const float* __restrict__ be1,
    const float* __restrict__ W,
    const float* __restrict__ bqkv,
    unsigned char* __restrict__ Qb,
    unsigned char* __restrict__ Kb,
    unsigned char* __restrict__ VbT)
{
  __shared__ __align__(16) unsigned short As[64 * 72];   // y bf16 [row][k]; aliased by Es
  __shared__ __align__(16) unsigned short Ws[128 * 72];  // W^T bf16 [n][k]
  unsigned char* Es = (unsigned char*)As;                // 8192B fp8 out staging
  const int tid = threadIdx.x, wv = tid >> 6, lane = tid & 63;
  const int col = lane & 15, quad = lane >> 4;
  const int bm = blockIdx.x & 127, bn = blockIdx.x >> 7;
  const int m0 = bm * 64, nw = bn * 128;

  // ---- A staging + LN ----
  const int c4 = tid & 15;
  float4 gv = *(const float4*)(g1 + c4 * 4);
  float4 bv = *(const float4*)(be1 + c4 * 4);
  #pragma unroll
  for (int s = 0; s < 4; ++s) {
    int idx = s * 256 + tid;
    int row = idx >> 4;
    float4 xv = *(const float4*)(x + (size_t)(m0 + row) * CC + c4 * 4);
    float ps = xv.x + xv.y + xv.z + xv.w;
    float ps2 = xv.x * xv.x + xv.y * xv.y + xv.z * xv.z + xv.w * xv.w;
    #pragma unroll
    for (int off = 8; off; off >>= 1) {
      ps += __shfl_xor(ps, off, 16);
      ps2 += __shfl_xor(ps2, off, 16);
    }
    float mean = ps * (1.0f / 64.0f);
    float var = ps2 * (1.0f / 64.0f) - mean * mean;
    float rs = rsqrtf(var + 1e-6f);
    uint2 packed;
    packed.x = pk2((xv.x - mean) * rs * gv.x + bv.x, (xv.y - mean) * rs * gv.y + bv.y);
    packed.y = pk2((xv.z - mean) * rs * gv.z + bv.z, (xv.w - mean) * rs * gv.w + bv.w);
    *(uint2*)&As[row * 72 + c4 * 4] = packed;
  }

  // ---- W staging ----
  {
    const int c_loc = tid & 127;
    const int kg = tid >> 7;
    const int ng = nw + c_loc;
    #pragma unroll
    for (int g = 0; g < 4; ++g) {
      float wv8[8];
      #pragma unroll
      for (int j = 0; j < 8; ++j) wv8[j] = W[(size_t)(kg * 32 + g * 8 + j) * 1536 + ng];
      uint4 u;
      u.x = pk2(wv8[0], wv8[1]); u.y = pk2(wv8[2], wv8[3]);
      u.z = pk2(wv8[4], wv8[5]); u.w = pk2(wv8[6], wv8[7]);
      *(uint4*)&Ws[c_loc * 72 + kg * 32 + g * 8] = u;
    }
  }
  __syncthreads();

  // ---- MFMA: 1 m-tile x 8 n-tiles, K=64 ----
  bf16x8 af0 = *(const bf16x8*)&As[(wv * 16 + col) * 72 + quad * 8];
  bf16x8 af1 = *(const bf16x8*)&As[(wv * 16 + col) * 72 + 32 + quad * 8];

  f32x4 acc[8];
  #pragma unroll
  for (int nt = 0; nt < 8; ++nt) acc[nt] = (f32x4){0.f, 0.f, 0.f, 0.f};
  #pragma unroll
  for (int nt = 0; nt < 8; ++nt) {
    bf16x8 b0 = *(const bf16x8*)&Ws[(nt * 16 + col) * 72 + quad * 8];
    bf16x8 b1 = *(const bf16x8*)&Ws[(nt * 16 + col) * 72 + 32 + quad * 8];
    acc[nt] = __builtin_amdgcn_mfma_f32_16x16x32_bf16(af0, b0, acc[nt], 0, 0, 0);
    acc[nt] = __builtin_amdgcn_mfma_f32_16x16x32_bf16(af1, b1, acc[nt], 0, 0, 0);
  }
  __syncthreads();  // all As reads done before Es (alias) is written

  // ---- epilogue: bias -> fp8 -> LDS staging -> coalesced flush ----
  const int bb = m0 >> 11;
  const int nloc = m0 & 2047;
  const int which = nw >> 9;            // block-uniform: 0=Q 1=K 2=V
  const int hbase = (nw >> 6) & 7;
  const int tloc = wv * 16 + quad * 4;  // local token of r=0

  if (which == 2) {
    // V: pack 4 tokens/dword into Es[hb][d][n-chunk], flush as 64B segments
    #pragma unroll
    for (int nt = 0; nt < 8; ++nt) {
      const int hb = nt >> 2, d0 = (nt & 3) * 16;
      const float bias = bqkv[nw + nt * 16 + col];
      int lo = __builtin_amdgcn_cvt_pk_fp8_f32(acc[nt][0] + bias, acc[nt][1] + bias, 0, false);
      int full = __builtin_amdgcn_cvt_pk_fp8_f32(acc[nt][2] + bias, acc[nt][3] + bias, lo, true);
      *(unsigned int*)&Es[hb * 4096 + (d0 + col) * 64 + tloc] = (unsigned int)full;
    }
    __syncthreads();
    const int d = tid >> 2, nseg = (tid & 3) * 16;
    #pragma unroll
    for (int hb = 0; hb < 2; ++hb) {
      size_t off = ((size_t)(bb * HH + hbase + hb) * CC + d) * NN + nloc + nseg;
      *(uint4*)(VbT + off) = *(const uint4*)&Es[hb * 4096 + tid * 16];
    }
  } else {
    // Q/K: fp8 bytes into Es[hb][token][d], flush 4KB contiguous per hb
    const float scale = (which == 0) ? QKSCALE : 1.0f;
    #pragma unroll
    for (int nt = 0; nt < 8; ++nt) {
      const int hb = nt >> 2, d0 = (nt & 3) * 16;
      const float bias = bqkv[nw + nt * 16 + col];
      #pragma unroll
      for (int r = 0; r < 4; ++r)
        Es[hb * 4096 + (tloc + r) * 64 + d0 + col] = f2fp8((acc[nt][r] + bias) * scale);
    }
    __syncthreads();
    unsigned char* dst = (which == 0) ? Qb : Kb;
    #pragma unroll
    for (int hb = 0; hb < 2; ++hb) {
      size_t off = ((size_t)(bb * HH + hbase + hb) * NN + nloc) * CC + tid * 16;
      *(uint4*)(dst + off) = *(const uint4*)&Es[hb * 4096 + tid * 16];
    }
  }
}

// ---------------- Kernel 2: fp8 flash attention, stride-88 LDS ----------------
// grid = 1024: bh(32) x qc(16, 128 q) x tc(2, 1024 t). block 256 = 4 waves x 32 q.
// S^T = K.Q^T; P^T B-frags via shfl (no LDS). O^T = V^T.P^T.
// lsum via ones-row MFMA; raw v_exp_f32.
__global__ __launch_bounds__(256) void k_attn(
    const unsigned char* __restrict__ Q,
    const unsigned char* __restrict__ K,
    const unsigned char* __restrict__ VT,
    const float* __restrict__ Wout,
    unsigned short* __restrict__ part,
    float* __restrict__ lsums)
{
  __shared__ __align__(16) unsigned char smem[27648];
  unsigned char* Ks = smem;                             // 64*88 = 5632
  unsigned char* Vt = smem + 5632;                      // [d][t] 80 rows * 88 = 7040
  unsigned short* Wb = (unsigned short*)smem;           // epi: 64*72*2 = 9216
  unsigned short* Ob = (unsigned short*)(smem + 9216);  // epi: 4*32*72*2 = 18432
  const int tid = threadIdx.x, wv = tid >> 6, lane = tid & 63;
  const int col = lane & 15, quad = lane >> 4;
  const int bid = blockIdx.x;
  const int tc = bid & 1, qc = (bid >> 1) & 15, bh = bid >> 5;
  const size_t base = (size_t)bh * NN * CC;
  const int q0 = qc * 128 + wv * 32;
  const int t0 = tc * 1024;
  const int srow = tid >> 2, sc16 = (tid & 3) << 4;

  // ones row (d=64) + zero rows (65..79) for the lsum MFMA
  if (tid < 80) {
    unsigned int fill = (tid == 0) ? 0x38383838u : 0u;  // row 64 = fp8 1.0
    // row 64+j gets fill for j==0; write 88B rows via dwords (11 per row)
    #pragma unroll
    for (int w8 = 0; w8 < 11; ++w8)
      *(unsigned int*)&Vt[(64 + (tid >> 0) % 16) * LSTR + 0] = 0u;  // placeholder overwritten below
  }
  // deterministic: zero rows 64..79 then set row 64 to ones
  {
    // 16 rows * 88B = 1408B; 256 threads x 8B covers 2048B
    int idx = tid * 8;
    if (idx < 16 * LSTR) {
      unsigned long long z = 0ull;
      *(unsigned long long*)&Vt[64 * LSTR + idx] = z;
    }
  }
  __syncthreads();
  if (tid < 11) *(unsigned int*)&Vt[64 * LSTR + tid * 4] = 0x38383838u;

  // Q B-frags (n = q-row = col, k = d = quad*8+j + 32*kh)
  long qf[2][2];
  #pragma unroll
  for (int mt = 0; mt < 2; ++mt)
    #pragma unroll
    for (int kh = 0; kh < 2; ++kh)
      qf[mt][kh] = *(const long*)(Q + base + (size_t)(q0 + mt * 16 + col) * CC + kh * 32 + quad * 8);

  f32x4 o[2][4];
  f32x4 ol[2];
  #pragma unroll
  for (int mt = 0; mt < 2; ++mt) {
    #pragma unroll
    for (int dt = 0; dt < 4; ++dt) o[mt][dt] = (f32x4){0.f, 0.f, 0.f, 0.f};
    ol[mt] = (f32x4){0.f, 0.f, 0.f, 0.f};
  }
  const int sl0 = ((quad & 1) << 5) + col;  // src lane quad'=2*(quad&1)
  const int sl1 = sl0 + 16;                 // quad'+1
  const bool hiq = (quad >= 2);

  for (int kt = 0; kt < 16; ++kt) {
    const int tb = t0 + kt * 64;
    {
      // 16B/thread from global; two b64 LDS writes (stride 88 is 8B-aligned)
      uint4 kv = *(const uint4*)(K + base + (size_t)(tb + srow) * CC + sc16);
      uint4 vv = *(const uint4*)(VT + base + (size_t)srow * NN + tb + sc16);
      *(uint2*)&Ks[srow * LSTR + sc16] = make_uint2(kv.x, kv.y);
      *(uint2*)&Ks[srow * LSTR + sc16 + 8] = make_uint2(kv.z, kv.w);
      *(uint2*)&Vt[srow * LSTR + sc16] = make_uint2(vv.x, vv.y);
      *(uint2*)&Vt[srow * LSTR + sc16 + 8] = make_uint2(vv.z, vv.w);
    }
    __syncthreads();

    // S^T tiles -> P fp8, packed per-lane
    unsigned int Dw[2][4];
    #pragma unroll
    for (int ct = 0; ct < 4; ++ct) {
      long k0 = *(const long*)&Ks[(ct * 16 + col) * LSTR + quad * 8];
      long k1 = *(const long*)&Ks[(ct * 16 + col) * LSTR + 32 + quad * 8];
      #pragma unroll
      for (int mt = 0; mt < 2; ++mt) {
        f32x4 a = (f32x4){0.f, 0.f, 0.f, 0.f};
        a = __builtin_amdgcn_mfma_f32_16x16x32_fp8_fp8(k0, qf[mt][0], a, 0, 0, 0);
        a = __builtin_amdgcn_mfma_f32_16x16x32_fp8_fp8(k1, qf[mt][1], a, 0, 0, 0);
        float p0 = __builtin_amdgcn_exp2f(a[0]);
        float p1 = __builtin_amdgcn_exp2f(a[1]);
        float p2 = __builtin_amdgcn_exp2f(a[2]);
        float p3 = __builtin_amdgcn_exp2f(a[3]);
        int lo = __builtin_amdgcn_cvt_pk_fp8_f32(p0, p1, 0, false);
        Dw[mt][ct] = (unsigned int)__builtin_amdgcn_cvt_pk_fp8_f32(p2, p3, lo, true);
      }
    }

    // O^T += V^T . P^T ; lsum via ones-row MFMA
    #pragma unroll
    for (int kh = 0; kh < 2; ++kh) {
      long pb[2];
      #pragma unroll
      for (int mt = 0; mt < 2; ++mt) {
        unsigned int a0 = (unsigned int)__shfl((int)Dw[mt][2 * kh], sl0, 64);
        unsigned int b0 = (unsigned int)__shfl((int)Dw[mt][2 * kh + 1], sl0, 64);
        unsigned int a1 = (unsigned int)__shfl((int)Dw[mt][2 * kh], sl1, 64);
        unsigned int b1 = (unsigned int)__shfl((int)Dw[mt][2 * kh + 1], sl1, 64);
        unsigned long lo = hiq ? b0 : a0;
        unsigned long hi = hiq ? b1 : a1;
        pb[mt] = (long)(lo | (hi << 32));
      }
      #pragma unroll
      for (int dt = 0; dt < 4; ++dt) {
        long vf = *(const long*)&Vt[(dt * 16 + col) * LSTR + kh * 32 + quad * 8];
        o[0][dt] = __builtin_amdgcn_mfma_f32_16x16x32_fp8_fp8(vf, pb[0], o[0][dt], 0, 0, 0);
        o[1][dt] = __builtin_amdgcn_mfma_f32_16x16x32_fp8_fp8(vf, pb[1], o[1][dt], 0, 0, 0);
      }
      long vl = *(const long*)&Vt[(64 + col) * LSTR + kh * 32 + quad * 8];
      ol[0] = __builtin_amdgcn_mfma_f32_16x16x32_fp8_fp8(vl, pb[0], ol[0], 0, 0, 0);
      ol[1] = __builtin_amdgcn_mfma_f32_16x16x32_fp8_fp8(vl, pb[1], ol[1], 0, 0, 0);
    }
    __syncthreads();
  }

  // l[q] from ones-row tile (quad 0, reg 0)
  const int h = bh & 7, b = bh >> 3;
  #pragma unroll
  for (int mt = 0; mt < 2; ++mt) {
    if (quad == 0)
      lsums[(size_t)(tc * 32 + bh) * NN + q0 + mt * 16 + col] = ol[mt][0];
  }

  // ---- fused per-head out-proj on UNNORMALIZED O ----
  {
    const int c = tid & 63, kg = tid >> 6;
    #pragma unroll
    for (int j = 0; j < 16; ++j)
      Wb[c * 72 + kg * 16 + j] = f2b(Wout[(size_t)(h * 64 + kg * 16 + j) * 64 + c]);
  }
  unsigned short* Obw = Ob + wv * (32 * 72);
  #pragma unroll
  for (int mt = 0; mt < 2; ++mt)
    #pragma unroll
    for (int dt = 0; dt < 4; ++dt) {
      uint2 u;
      u.x = pk2(o[mt][dt][0], o[mt][dt][1]);
      u.y = pk2(o[mt][dt][2], o[mt][dt][3]);
      *(uint2*)&Obw[(mt * 16 + col) * 72 + dt * 16 + quad * 4] = u;
    }
  __syncthreads();

  #pragma unroll
  for (int mt = 0; mt < 2; ++mt) {
    bf16x8 oa0 = *(const bf16x8*)&Obw[(mt * 16 + col) * 72 + quad * 8];
    bf16x8 oa1 = *(const bf16x8*)&Obw[(mt * 16 + col) * 72 + 32 + quad * 8];
    #pragma unroll
    for (int nt = 0; nt < 4; ++nt) {
      bf16x8 bw0 = *(const bf16x8*)&Wb[(nt * 16 + col) * 72 + quad * 8];
      bf16x8 bw1 = *(const bf16x8*)&Wb[(nt * 16 + col) * 72 + 32 + quad * 8];
      f32x4 ac = (f32x4){0.f, 0.f, 0.f, 0.f};
      ac = __builtin_amdgcn_mfma_f32_16x16x32_bf16(oa0, bw0, ac, 0, 0, 0);
      ac = __builtin_amdgcn_mfma_f32_16x16x32_bf16(oa1, bw1, ac, 0, 0, 0);
      #pragma unroll
      for (int r = 0; r < 4; ++r) {
        int n = q0 + mt * 16 + quad * 4 + r;
        part[((size_t)(tc * 32 + bh) * NN + n) * CC + nt * 16 + col] = f2b(ac[r]);
      }
    }
  }
}

// ---------------- Kernel 3: sum partials/l + GELU + res + LN2 + MLP + res ----------------
// grid 1024, block 256 = 4 waves, 2 tokens/wave. W1/W2 staged bf16.
__global__ __launch_bounds__(256) void k_post(
    const unsigned short* __restrict__ part,
    const float* __restrict__ lsums,
    const float* __restrict__ x,
    const float* __restrict__ bout,
    const float* __restrict__ g2,
    const float* __restrict__ be2,
    const float* __restrict__ W1,
    const float* __restrict__ b1,
    const float* __restrict__ W2,
    const float* __restrict__ b2v,
    float* __restrict__ out)
{
  __shared__ __align__(16) unsigned short Ws1[64 * 64];
  __shared__ __align__(16) unsigned short Ws2[64 * 64];
  __shared__ float ys[8][64], hs[8][64];
  const int tid = threadIdx.x, wid = tid >> 6, lane = tid & 63;
  const int w2 = wid * 2;
  const int tk0 = blockIdx.x * 8 + w2;

  #pragma unroll
  for (int p = 0; p < 4; ++p) {
    int idx = p * 256 + tid;
    float4 a1 = *(const float4*)(W1 + idx * 4);
    float4 a2 = *(const float4*)(W2 + idx * 4);
    uint2 u1; u1.x = pk2(a1.x, a1.y); u1.y = pk2(a1.z, a1.w);
    uint2 u2; u2.x = pk2(a2.x, a2.y); u2.y = pk2(a2.z, a2.w);
    *(uint2*)&Ws1[idx * 4] = u1;
    *(uint2*)&Ws2[idx * 4] = u2;
  }

  const float boutl = bout[lane];
  const float g2l = g2[lane], be2l = be2[lane];
  float x2v[2];
  #pragma unroll
  for (int t = 0; t < 2; ++t) {
    const int tk = tk0 + t;
    const int b = tk >> 11, n = tk & 2047;
    float proj = 0.f;
    #pragma unroll
    for (int h = 0; h < 8; ++h) {
      size_t i0 = (size_t)(b * HH + h) * NN + n;
      size_t i1 = i0 + (size_t)32 * NN;
      float p = b2f(part[i0 * CC + lane]) + b2f(part[i1 * CC + lane]);
      float l = lsums[i0] + lsums[i1];
      proj += p * __builtin_amdgcn_rcpf(l);
    }
    float a = gelu_f(proj + boutl);
    float x2 = a + x[(size_t)tk * CC + lane];
    x2v[t] = x2;
    float s = x2;
    #pragma unroll
    for (int off = 32; off; off >>= 1) s += __shfl_xor(s, off, 64);
    float mean = s * (1.0f / 64.0f);
    float d = x2 - mean;
    float vs = d * d;
    #pragma unroll
    for (int off = 32; off; off >>= 1) vs += __shfl_xor(vs, off, 64);
    float var = vs * (1.0f / 64.0f);
    ys[w2 + t][lane] = d * rsqrtf(var + 1e-6f) * g2l + be2l;
  }
  __syncthreads();  // covers W staging + ys

  float acc2[2] = {0.f, 0.f};
  #pragma unroll 8
  for (int c = 0; c < 64; ++c) {
    float w = b2f(Ws1[c * 64 + lane]);
    acc2[0] += ys[w2][c] * w;
    acc2[1] += ys[w2 + 1][c] * w;
  }
  const float b1l = b1[lane];
  hs[w2][lane] = gelu_f(acc2[0] + b1l);      // same-wave LDS rows: no barrier
  hs[w2 + 1][lane] = gelu_f(acc2[1] + b1l);

  float acc3[2] = {0.f, 0.f};
  #pragma unroll 8
  for (int c = 0; c < 64; ++c) {
    float w = b2f(Ws2[c * 64 + lane]);
    acc3[0] += hs[w2][c] * w;
    acc3[1] += hs[w2 + 1][c] * w;
  }
  const float b2l = b2v[lane];
  #pragma unroll
  for (int t = 0; t < 2; ++t)
    out[(size_t)(tk0 + t) * CC + lane] = acc3[t] + b2l + x2v[t];
}

extern "C" void kernel_launch(void* const* d_in, const int* in_sizes, int n_in,
                              void* d_out, int out_size, void* d_ws, size_t ws_size,
                              hipStream_t stream) {
  const float* x    = (const float*)d_in[0];
  const float* g1   = (const float*)d_in[1];
  const float* be1  = (const float*)d_in[2];
  const float* Wqkv = (const float*)d_in[3];
  const float* bqkv = (const float*)d_in[4];
  const float* Wout = (const float*)d_in[5];
  const float* bout = (const float*)d_in[6];
  const float* g2   = (const float*)d_in[7];
  const float* be2  = (const float*)d_in[8];
  const float* W1   = (const float*)d_in[9];
  const float* b1   = (const float*)d_in[10];
  const float* W2   = (const float*)d_in[11];
  const float* b2   = (const float*)d_in[12];
  float* out = (float*)d_out;

  unsigned char* wsb = (unsigned char*)d_ws;
  const size_t SZ = (size_t)4 * HH * NN * CC;  // 4 MiB
  unsigned char* Qb   = wsb;
  unsigned char* Kb   = wsb + SZ;
  unsigned char* VbT  = wsb + 2 * SZ;
  unsigned short* part = (unsigned short*)(wsb + 3 * SZ);      // 16 MiB bf16
  float* lsums         = (float*)(wsb + 3 * SZ + 4 * SZ);      // 1 MiB f32

  k_ln_qkv<<<1536, 256, 0, stream>>>(x, g1, be1, Wqkv, bqkv, Qb, Kb, VbT);
  k_attn<<<1024, 256, 0, stream>>>(Qb, Kb, VbT, Wout, part, lsums);
  k_post<<<1024, 256, 0, stream>>>(part, lsums, x, bout, g2, be2, W1, b1, W2, b2, out);
}